// Round 2
// baseline (355.142 us; speedup 1.0000x reference)
//
#include <hip/hip_runtime.h>
#include <hip/hip_bf16.h>

using f32x4  = __attribute__((ext_vector_type(4))) float;
using short8 = __attribute__((ext_vector_type(8))) short;
using us8    = __attribute__((ext_vector_type(8))) unsigned short;
using us4    = __attribute__((ext_vector_type(4))) unsigned short;
using fl4    = __attribute__((ext_vector_type(4))) float;

__device__ __forceinline__ unsigned short f2bf(float f){
    unsigned u = __builtin_bit_cast(unsigned, f);
    u += 0x7FFF + ((u >> 16) & 1);
    return (unsigned short)(u >> 16);
}

// C = A @ W^T + bias.  A: [M,K] (fp32 or bf16), W: [N,K] fp32, out: [M,N] (bf16 or fp32)
// Tile 128x128, BK=64, 256 threads (4 waves, 2x2), mfma_f32_16x16x32_bf16.
template<bool ABF16, bool OBF16>
__global__ __launch_bounds__(256, 2)
void gemm_bt(const void* __restrict__ A0, const void* __restrict__ A1, const void* __restrict__ A2,
             const float* __restrict__ W0, const float* __restrict__ W1, const float* __restrict__ W2,
             const float* __restrict__ B0, const float* __restrict__ B1, const float* __restrict__ B2,
             void* __restrict__ O0, void* __restrict__ O1, void* __restrict__ O2,
             int M, int N, int K)
{
    const int z = blockIdx.z;
    const void*  Ap = (z == 0) ? A0 : (z == 1) ? A1 : A2;
    const float* Wp = (z == 0) ? W0 : (z == 1) ? W1 : W2;
    const float* bp = (z == 0) ? B0 : (z == 1) ? B1 : B2;
    void*        Op = (z == 0) ? O0 : (z == 1) ? O1 : O2;

    const int tid  = threadIdx.x;
    const int lane = tid & 63;
    const int w    = tid >> 6;
    const int wr   = w >> 1, wc = w & 1;
    const int l15  = lane & 15, l4 = lane >> 4;
    const int bm   = blockIdx.y, bn = blockIdx.x;

    __shared__ unsigned short As[128 * 64];
    __shared__ unsigned short Bs[128 * 64];

    f32x4 acc[4][4];
    #pragma unroll
    for (int i = 0; i < 4; i++)
        #pragma unroll
        for (int j = 0; j < 4; j++) acc[i][j] = (f32x4){0.f, 0.f, 0.f, 0.f};

    fl4 ar_f[8]; us4 ar_h[8]; fl4 br_f[8];
    const int KT = K >> 6;

    auto loadA = [&](int kt) {
        #pragma unroll
        for (int i = 0; i < 8; i++) {
            int c = i * 256 + tid;
            int row = c >> 4, col = (c & 15) * 4;
            if constexpr (ABF16)
                ar_h[i] = *(const us4*)((const unsigned short*)Ap + (size_t)(bm * 128 + row) * K + kt * 64 + col);
            else
                ar_f[i] = *(const fl4*)((const float*)Ap + (size_t)(bm * 128 + row) * K + kt * 64 + col);
        }
    };
    auto loadB = [&](int kt) {
        #pragma unroll
        for (int i = 0; i < 8; i++) {
            int c = i * 256 + tid;
            int row = c >> 4, col = (c & 15) * 4;
            br_f[i] = *(const fl4*)(Wp + (size_t)(bn * 128 + row) * K + kt * 64 + col);
        }
    };
    auto writeLDS = [&]() {
        #pragma unroll
        for (int i = 0; i < 8; i++) {
            int c = i * 256 + tid;
            int off = c * 4;
            us4 a;
            if constexpr (ABF16) a = ar_h[i];
            else a = (us4){ f2bf(ar_f[i][0]), f2bf(ar_f[i][1]), f2bf(ar_f[i][2]), f2bf(ar_f[i][3]) };
            *(us4*)&As[off] = a;
            us4 b = (us4){ f2bf(br_f[i][0]), f2bf(br_f[i][1]), f2bf(br_f[i][2]), f2bf(br_f[i][3]) };
            *(us4*)&Bs[off] = b;
        }
    };

    loadA(0); loadB(0);
    for (int kt = 0; kt < KT; ++kt) {
        __syncthreads();
        writeLDS();
        __syncthreads();
        if (kt + 1 < KT) { loadA(kt + 1); loadB(kt + 1); }

        short8 af[4][2], bfr[4][2];
        #pragma unroll
        for (int mf = 0; mf < 4; mf++)
            #pragma unroll
            for (int kf = 0; kf < 2; kf++)
                af[mf][kf] = *(const short8*)&As[(wr * 64 + mf * 16 + l15) * 64 + kf * 32 + l4 * 8];
        #pragma unroll
        for (int nf = 0; nf < 4; nf++)
            #pragma unroll
            for (int kf = 0; kf < 2; kf++)
                bfr[nf][kf] = *(const short8*)&Bs[(wc * 64 + nf * 16 + l15) * 64 + kf * 32 + l4 * 8];
        #pragma unroll
        for (int mf = 0; mf < 4; mf++)
            #pragma unroll
            for (int nf = 0; nf < 4; nf++)
                #pragma unroll
                for (int kf = 0; kf < 2; kf++)
                    acc[mf][nf] = __builtin_amdgcn_mfma_f32_16x16x32_bf16(af[mf][kf], bfr[nf][kf], acc[mf][nf], 0, 0, 0);
    }

    #pragma unroll
    for (int mf = 0; mf < 4; mf++) {
        int row = bm * 128 + wr * 64 + mf * 16 + l4 * 4;
        #pragma unroll
        for (int nf = 0; nf < 4; nf++) {
            int col = bn * 128 + wc * 64 + nf * 16 + l15;
            float bv = bp[col];
            #pragma unroll
            for (int r = 0; r < 4; r++) {
                float vv = acc[mf][nf][r] + bv;
                if constexpr (OBF16)
                    ((unsigned short*)Op)[(size_t)(row + r) * N + col] = f2bf(vv);
                else
                    ((float*)Op)[(size_t)(row + r) * N + col] = vv;
            }
        }
    }
}

// Causal flash attention. Q,K,V projected, bf16, [B,S,D] with head slice h*64.
// Block: 256 threads = 4 waves, each wave 32 q-rows (2 m-frags); KV tiles of 64.
__global__ __launch_bounds__(256, 2)
void attn_causal(const unsigned short* __restrict__ Qp,
                 const unsigned short* __restrict__ Kp,
                 const unsigned short* __restrict__ Vp,
                 unsigned short* __restrict__ Ctx)
{
    const int S = 2048, D = 1024;
    const int bh = blockIdx.x, b = bh >> 4, h = bh & 15;
    const int qt = blockIdx.y;
    const int tid = threadIdx.x, w = tid >> 6, lane = tid & 63;
    const int l15 = lane & 15, l4 = lane >> 4;
    const int qrow_base = qt * 128 + w * 32;

    __shared__ unsigned short Ks[64 * 64];
    __shared__ unsigned short Vt[64 * 64];
    __shared__ unsigned short Ps[4][32 * 64];

    short8 qf[2][2];
    #pragma unroll
    for (int mf = 0; mf < 2; mf++)
        #pragma unroll
        for (int kf = 0; kf < 2; kf++) {
            int row = qrow_base + mf * 16 + l15;
            qf[mf][kf] = *(const short8*)(Qp + (size_t)(b * S + row) * D + h * 64 + kf * 32 + l4 * 8);
        }

    float mrow[2][4], lrow[2][4];
    f32x4 oacc[2][4];
    #pragma unroll
    for (int mf = 0; mf < 2; mf++)
        #pragma unroll
        for (int r = 0; r < 4; r++) { mrow[mf][r] = -3.0e38f; lrow[mf][r] = 0.f; }
    #pragma unroll
    for (int mf = 0; mf < 2; mf++)
        #pragma unroll
        for (int df = 0; df < 4; df++) oacc[mf][df] = (f32x4){0.f, 0.f, 0.f, 0.f};

    const float sc = 0.125f * 1.44269504088896f;  // 1/sqrt(64) * log2(e)
    const int nt = 2 * (qt + 1);

    for (int t = 0; t < nt; ++t) {
        const int kv0 = t * 64;
        // stage K rows and V transposed
        #pragma unroll
        for (int i = 0; i < 2; i++) {
            int c = i * 256 + tid;
            int r = c >> 3, d0 = (c & 7) * 8;
            us8 kv = *(const us8*)(Kp + (size_t)(b * S + kv0 + r) * D + h * 64 + d0);
            *(us8*)&Ks[r * 64 + d0] = kv;
            us8 vv = *(const us8*)(Vp + (size_t)(b * S + kv0 + r) * D + h * 64 + d0);
            #pragma unroll
            for (int j = 0; j < 8; j++) Vt[(d0 + j) * 64 + r] = vv[j];
        }
        __syncthreads();

        // S = Q K^T
        f32x4 sf[2][4];
        #pragma unroll
        for (int mf = 0; mf < 2; mf++)
            #pragma unroll
            for (int nf = 0; nf < 4; nf++) sf[mf][nf] = (f32x4){0.f, 0.f, 0.f, 0.f};
        #pragma unroll
        for (int nf = 0; nf < 4; nf++)
            #pragma unroll
            for (int kf = 0; kf < 2; kf++) {
                short8 kfrag = *(const short8*)&Ks[(nf * 16 + l15) * 64 + kf * 32 + l4 * 8];
                #pragma unroll
                for (int mf = 0; mf < 2; mf++)
                    sf[mf][nf] = __builtin_amdgcn_mfma_f32_16x16x32_bf16(qf[mf][kf], kfrag, sf[mf][nf], 0, 0, 0);
            }

        // mask needed if highest col (kv0+63) can exceed LOWEST row (qrow_base)
        const bool domask = (kv0 + 63 > qrow_base);
        #pragma unroll
        for (int mf = 0; mf < 2; mf++) {
            float p[4][4];
            #pragma unroll
            for (int nf = 0; nf < 4; nf++)
                #pragma unroll
                for (int r = 0; r < 4; r++) {
                    float x = sf[mf][nf][r] * sc;
                    if (domask) {
                        int col = kv0 + nf * 16 + l15;
                        int row = qrow_base + mf * 16 + l4 * 4 + r;
                        if (col > row) x = -3.0e38f;
                    }
                    p[nf][r] = x;
                }
            #pragma unroll
            for (int r = 0; r < 4; r++) {
                float pm = fmaxf(fmaxf(p[0][r], p[1][r]), fmaxf(p[2][r], p[3][r]));
                pm = fmaxf(pm, __shfl_xor(pm, 1));
                pm = fmaxf(pm, __shfl_xor(pm, 2));
                pm = fmaxf(pm, __shfl_xor(pm, 4));
                pm = fmaxf(pm, __shfl_xor(pm, 8));
                float mo = mrow[mf][r];
                float mn = fmaxf(mo, pm);
                float fs = exp2f(mo - mn);
                float ps = 0.f;
                #pragma unroll
                for (int nf = 0; nf < 4; nf++) { float e = exp2f(p[nf][r] - mn); p[nf][r] = e; ps += e; }
                ps += __shfl_xor(ps, 1); ps += __shfl_xor(ps, 2);
                ps += __shfl_xor(ps, 4); ps += __shfl_xor(ps, 8);
                lrow[mf][r] = lrow[mf][r] * fs + ps;
                mrow[mf][r] = mn;
                #pragma unroll
                for (int df = 0; df < 4; df++) oacc[mf][df][r] *= fs;
            }
            #pragma unroll
            for (int nf = 0; nf < 4; nf++)
                #pragma unroll
                for (int r = 0; r < 4; r++)
                    Ps[w][(mf * 16 + l4 * 4 + r) * 64 + nf * 16 + l15] = f2bf(p[nf][r]);
        }
        __syncthreads();

        // O += P V
        #pragma unroll
        for (int kf = 0; kf < 2; kf++) {
            short8 pa[2];
            #pragma unroll
            for (int mf = 0; mf < 2; mf++)
                pa[mf] = *(const short8*)&Ps[w][(mf * 16 + l15) * 64 + kf * 32 + l4 * 8];
            #pragma unroll
            for (int df = 0; df < 4; df++) {
                short8 vb = *(const short8*)&Vt[(df * 16 + l15) * 64 + kf * 32 + l4 * 8];
                #pragma unroll
                for (int mf = 0; mf < 2; mf++)
                    oacc[mf][df] = __builtin_amdgcn_mfma_f32_16x16x32_bf16(pa[mf], vb, oacc[mf][df], 0, 0, 0);
            }
        }
        __syncthreads();
    }

    #pragma unroll
    for (int mf = 0; mf < 2; mf++)
        #pragma unroll
        for (int df = 0; df < 4; df++)
            #pragma unroll
            for (int r = 0; r < 4; r++) {
                int row = qrow_base + mf * 16 + l4 * 4 + r;
                float vv = oacc[mf][df][r] / lrow[mf][r];
                Ctx[(size_t)(b * S + row) * D + h * 64 + df * 16 + l15] = f2bf(vv);
            }
}

extern "C" void kernel_launch(void* const* d_in, const int* in_sizes, int n_in,
                              void* d_out, int out_size, void* d_ws, size_t ws_size,
                              hipStream_t stream)
{
    const float* q  = (const float*)d_in[0];
    const float* k  = (const float*)d_in[1];
    const float* v  = (const float*)d_in[2];
    const float* Wq = (const float*)d_in[3];
    const float* bq = (const float*)d_in[4];
    const float* Wk = (const float*)d_in[5];
    const float* bk = (const float*)d_in[6];
    const float* Wv = (const float*)d_in[7];
    const float* bv = (const float*)d_in[8];
    const float* Wo = (const float*)d_in[9];
    const float* bo = (const float*)d_in[10];

    const int M = 4096, N = 1024, K = 1024;
    unsigned short* Qp = (unsigned short*)d_ws;            // 4096x1024 bf16
    unsigned short* Kp = Qp + (size_t)M * N;
    unsigned short* Vp = Kp + (size_t)M * N;
    unsigned short* Ct = Vp + (size_t)M * N;               // total 33.6 MB

    dim3 g1(N / 128, M / 128, 3);
    gemm_bt<false, true><<<g1, 256, 0, stream>>>(q, k, v, Wq, Wk, Wv, bq, bk, bv,
                                                 Qp, Kp, Vp, M, N, K);
    dim3 g2(32, 16);
    attn_causal<<<g2, 256, 0, stream>>>(Qp, Kp, Vp, Ct);

    dim3 g3(N / 128, M / 128, 1);
    gemm_bt<true, false><<<g3, 256, 0, stream>>>(Ct, Ct, Ct, Wo, Wo, Wo, bo, bo, bo,
                                                 d_out, d_out, d_out, M, N, K);
}

// Round 3
// 345.317 us; speedup vs baseline: 1.0285x; 1.0285x over previous
//
#include <hip/hip_runtime.h>
#include <hip/hip_bf16.h>

using f32x4  = __attribute__((ext_vector_type(4))) float;
using short8 = __attribute__((ext_vector_type(8))) short;
using us8    = __attribute__((ext_vector_type(8))) unsigned short;
using us4    = __attribute__((ext_vector_type(4))) unsigned short;
using fl4    = __attribute__((ext_vector_type(4))) float;

__device__ __forceinline__ unsigned short f2bf(float f){
    unsigned u = __builtin_bit_cast(unsigned, f);
    u += 0x7FFF + ((u >> 16) & 1);
    return (unsigned short)(u >> 16);
}

__device__ __forceinline__ void gload16(const unsigned short* g, unsigned short* l) {
    __builtin_amdgcn_global_load_lds(
        (const __attribute__((address_space(1))) unsigned int*)g,
        (__attribute__((address_space(3))) unsigned int*)l, 16, 0, 0);
}

// ---------------- fp32 -> bf16 conversion (z picks array) ----------------
__global__ __launch_bounds__(256)
void conv_bf16(const float* __restrict__ s0, const float* __restrict__ s1, const float* __restrict__ s2,
               const float* __restrict__ s3, const float* __restrict__ s4, const float* __restrict__ s5,
               const float* __restrict__ s6,
               unsigned short* __restrict__ d0, unsigned short* __restrict__ d1, unsigned short* __restrict__ d2,
               unsigned short* __restrict__ d3, unsigned short* __restrict__ d4, unsigned short* __restrict__ d5,
               unsigned short* __restrict__ d6,
               int nbig4, int nsml4)
{
    const int z = blockIdx.z;
    const float* s = (z==0)?s0:(z==1)?s1:(z==2)?s2:(z==3)?s3:(z==4)?s4:(z==5)?s5:s6;
    unsigned short* d = (z==0)?d0:(z==1)?d1:(z==2)?d2:(z==3)?d3:(z==4)?d4:(z==5)?d5:d6;
    const int n4 = (z < 3) ? nbig4 : nsml4;
    const int stride = gridDim.x * blockDim.x;
    for (int i = blockIdx.x * blockDim.x + threadIdx.x; i < n4; i += stride) {
        fl4 v = ((const fl4*)s)[i];
        us4 o = { f2bf(v[0]), f2bf(v[1]), f2bf(v[2]), f2bf(v[3]) };
        ((us4*)d)[i] = o;
    }
}

// ---------------- bf16 GEMM: C = A @ W^T + bias (m97 structure) ----------------
// A [M,K] bf16, W [N,K] bf16, out [M,N] bf16 or fp32. 128x128 tile, BK=64,
// 256 threads (4 waves 2x2), global_load_lds width-16 staging, linear LDS.
template<bool OBF16>
__global__ __launch_bounds__(256, 2)
void gemm_bf16(const unsigned short* __restrict__ A0, const unsigned short* __restrict__ A1,
               const unsigned short* __restrict__ A2,
               const unsigned short* __restrict__ W0, const unsigned short* __restrict__ W1,
               const unsigned short* __restrict__ W2,
               const float* __restrict__ B0, const float* __restrict__ B1, const float* __restrict__ B2,
               void* __restrict__ O0, void* __restrict__ O1, void* __restrict__ O2,
               int M, int N, int K)
{
    const int z = blockIdx.z;
    const unsigned short* Ap = (z==0)?A0:(z==1)?A1:A2;
    const unsigned short* Wp = (z==0)?W0:(z==1)?W1:W2;
    const float* bp = (z==0)?B0:(z==1)?B1:B2;
    void* Op = (z==0)?O0:(z==1)?O1:O2;

    const int tid = threadIdx.x, lane = tid & 63, w = tid >> 6;
    const int wr = w >> 1, wc = w & 1;
    const int l15 = lane & 15, l4 = lane >> 4;
    const int bm = blockIdx.y, bn = blockIdx.x;

    __shared__ unsigned short As[128 * 64];
    __shared__ unsigned short Bs[128 * 64];

    f32x4 acc[4][4];
    #pragma unroll
    for (int i = 0; i < 4; i++)
        #pragma unroll
        for (int j = 0; j < 4; j++) acc[i][j] = (f32x4){0.f, 0.f, 0.f, 0.f};

    const int KT = K >> 6;
    const int srow = lane >> 3;        // 0..7 within chunk
    const int scol = (lane & 7) * 8;   // bf16 col

    for (int kt = 0; kt < KT; ++kt) {
        __syncthreads();   // all waves done reading LDS of previous tile
        #pragma unroll
        for (int i = 0; i < 4; i++) {
            const int chunk = w * 4 + i;           // wave-uniform
            const int row = chunk * 8 + srow;
            gload16(Ap + (size_t)(bm * 128 + row) * K + kt * 64 + scol, &As[chunk * 512]);
            gload16(Wp + (size_t)(bn * 128 + row) * K + kt * 64 + scol, &Bs[chunk * 512]);
        }
        __syncthreads();   // drains vmcnt -> LDS tiles ready

        short8 af[4][2], bfr[4][2];
        #pragma unroll
        for (int mf = 0; mf < 4; mf++)
            #pragma unroll
            for (int kf = 0; kf < 2; kf++)
                af[mf][kf] = *(const short8*)&As[(wr * 64 + mf * 16 + l15) * 64 + kf * 32 + l4 * 8];
        #pragma unroll
        for (int nf = 0; nf < 4; nf++)
            #pragma unroll
            for (int kf = 0; kf < 2; kf++)
                bfr[nf][kf] = *(const short8*)&Bs[(wc * 64 + nf * 16 + l15) * 64 + kf * 32 + l4 * 8];
        #pragma unroll
        for (int mf = 0; mf < 4; mf++)
            #pragma unroll
            for (int nf = 0; nf < 4; nf++)
                #pragma unroll
                for (int kf = 0; kf < 2; kf++)
                    acc[mf][nf] = __builtin_amdgcn_mfma_f32_16x16x32_bf16(af[mf][kf], bfr[nf][kf], acc[mf][nf], 0, 0, 0);
    }

    #pragma unroll
    for (int mf = 0; mf < 4; mf++) {
        int row = bm * 128 + wr * 64 + mf * 16 + l4 * 4;
        #pragma unroll
        for (int nf = 0; nf < 4; nf++) {
            int col = bn * 128 + wc * 64 + nf * 16 + l15;
            float bv = bp[col];
            #pragma unroll
            for (int r = 0; r < 4; r++) {
                float vv = acc[mf][nf][r] + bv;
                if constexpr (OBF16)
                    ((unsigned short*)Op)[(size_t)(row + r) * N + col] = f2bf(vv);
                else
                    ((float*)Op)[(size_t)(row + r) * N + col] = vv;
            }
        }
    }
}

// ---------------- causal flash attention ----------------
// 64 q-rows/block (4 waves x 16 rows), KV tiles of 64, XOR-swizzled LDS,
// register prefetch of next K/V tile. qt reversed so longest blocks launch first.
__global__ __launch_bounds__(256, 2)
void attn_causal(const unsigned short* __restrict__ Qp,
                 const unsigned short* __restrict__ Kp,
                 const unsigned short* __restrict__ Vp,
                 unsigned short* __restrict__ Ctx)
{
    const int S = 2048, D = 1024;
    const int bh = blockIdx.y, b = bh >> 4, h = bh & 15;
    const int qt = gridDim.x - 1 - blockIdx.x;
    const int tid = threadIdx.x, w = tid >> 6, lane = tid & 63;
    const int l15 = lane & 15, l4 = lane >> 4;
    const int qrow_base = qt * 64 + w * 16;

    __shared__ unsigned short Ks[64 * 64];      // [kv][d], row-swizzled
    __shared__ unsigned short Vt[64 * 64];      // [d][kv], d-group swizzled
    __shared__ unsigned short Ps[4][16 * 64];   // per-wave P, row-swizzled

    short8 qf[2];
    #pragma unroll
    for (int kf = 0; kf < 2; kf++)
        qf[kf] = *(const short8*)(Qp + (size_t)(b * S + qrow_base + l15) * D + h * 64 + kf * 32 + l4 * 8);

    float mrow[4], lrow[4];
    f32x4 oacc[4];
    #pragma unroll
    for (int r = 0; r < 4; r++) { mrow[r] = -3.0e38f; lrow[r] = 0.f; }
    #pragma unroll
    for (int df = 0; df < 4; df++) oacc[df] = (f32x4){0.f, 0.f, 0.f, 0.f};

    const float sc = 0.125f * 1.44269504088896f;  // 1/sqrt(64) * log2(e)
    const int nt = qt + 1;

    us8 krg[2], vrg[2];
    {
        #pragma unroll
        for (int i = 0; i < 2; i++) {
            int cc = i * 256 + tid, r = cc >> 3, d0 = (cc & 7) * 8;
            krg[i] = *(const us8*)(Kp + (size_t)(b * S + r) * D + h * 64 + d0);
            vrg[i] = *(const us8*)(Vp + (size_t)(b * S + r) * D + h * 64 + d0);
        }
    }

    for (int t = 0; t < nt; ++t) {
        // write staged regs -> LDS (swizzled)
        #pragma unroll
        for (int i = 0; i < 2; i++) {
            int cc = i * 256 + tid, r = cc >> 3, e = cc & 7, d0 = e * 8;
            int koff = (r * 128 + d0 * 2) ^ ((r & 7) << 4);
            *(us8*)((char*)Ks + koff) = krg[i];
            #pragma unroll
            for (int j = 0; j < 8; j++) {
                int voff = ((d0 + j) * 128 + r * 2) ^ (e << 4);   // e == ((d0+j)>>3)&7
                *(unsigned short*)((char*)Vt + voff) = vrg[i][j];
            }
        }
        __syncthreads();

        if (t + 1 < nt) {
            #pragma unroll
            for (int i = 0; i < 2; i++) {
                int cc = i * 256 + tid, r = cc >> 3, d0 = (cc & 7) * 8;
                krg[i] = *(const us8*)(Kp + (size_t)(b * S + (t + 1) * 64 + r) * D + h * 64 + d0);
                vrg[i] = *(const us8*)(Vp + (size_t)(b * S + (t + 1) * 64 + r) * D + h * 64 + d0);
            }
        }

        // S = Q K^T   (16 q-rows x 64 cols)
        f32x4 sf[4];
        #pragma unroll
        for (int nf = 0; nf < 4; nf++) sf[nf] = (f32x4){0.f, 0.f, 0.f, 0.f};
        #pragma unroll
        for (int nf = 0; nf < 4; nf++)
            #pragma unroll
            for (int kf = 0; kf < 2; kf++) {
                int row = nf * 16 + l15;
                int off = (row * 128 + kf * 64 + l4 * 16) ^ ((row & 7) << 4);
                short8 kfrag = *(const short8*)((const char*)Ks + off);
                sf[nf] = __builtin_amdgcn_mfma_f32_16x16x32_bf16(qf[kf], kfrag, sf[nf], 0, 0, 0);
            }

        const bool domask = (t == nt - 1);
        float p[4][4];
        #pragma unroll
        for (int nf = 0; nf < 4; nf++)
            #pragma unroll
            for (int r = 0; r < 4; r++) {
                float x = sf[nf][r] * sc;
                if (domask) {
                    int col = t * 64 + nf * 16 + l15;
                    int row = qrow_base + l4 * 4 + r;
                    if (col > row) x = -3.0e38f;
                }
                p[nf][r] = x;
            }
        #pragma unroll
        for (int r = 0; r < 4; r++) {
            float pm = fmaxf(fmaxf(p[0][r], p[1][r]), fmaxf(p[2][r], p[3][r]));
            pm = fmaxf(pm, __shfl_xor(pm, 1));
            pm = fmaxf(pm, __shfl_xor(pm, 2));
            pm = fmaxf(pm, __shfl_xor(pm, 4));
            pm = fmaxf(pm, __shfl_xor(pm, 8));
            float mo = mrow[r];
            float mn = fmaxf(mo, pm);
            float fs = exp2f(mo - mn);
            float ps = 0.f;
            #pragma unroll
            for (int nf = 0; nf < 4; nf++) { float e = exp2f(p[nf][r] - mn); p[nf][r] = e; ps += e; }
            ps += __shfl_xor(ps, 1); ps += __shfl_xor(ps, 2);
            ps += __shfl_xor(ps, 4); ps += __shfl_xor(ps, 8);
            lrow[r] = lrow[r] * fs + ps;
            mrow[r] = mn;
            #pragma unroll
            for (int df = 0; df < 4; df++) oacc[df][r] *= fs;
        }
        #pragma unroll
        for (int nf = 0; nf < 4; nf++)
            #pragma unroll
            for (int r = 0; r < 4; r++) {
                int row = l4 * 4 + r;
                int off = (row * 128 + (nf * 16 + l15) * 2) ^ ((row & 7) << 4);
                *(unsigned short*)((char*)Ps[w] + off) = f2bf(p[nf][r]);
            }

        // O += P V
        #pragma unroll
        for (int kf = 0; kf < 2; kf++) {
            int offp = (l15 * 128 + kf * 64 + l4 * 16) ^ ((l15 & 7) << 4);
            short8 pa = *(const short8*)((const char*)Ps[w] + offp);
            #pragma unroll
            for (int df = 0; df < 4; df++) {
                int d = df * 16 + l15;
                int offv = (d * 128 + kf * 64 + l4 * 16) ^ (((d >> 3) & 7) << 4);
                short8 vb = *(const short8*)((const char*)Vt + offv);
                oacc[df] = __builtin_amdgcn_mfma_f32_16x16x32_bf16(pa, vb, oacc[df], 0, 0, 0);
            }
        }
        __syncthreads();
    }

    #pragma unroll
    for (int df = 0; df < 4; df++)
        #pragma unroll
        for (int r = 0; r < 4; r++) {
            int row = qrow_base + l4 * 4 + r;
            float vv = oacc[df][r] / lrow[r];
            Ctx[(size_t)(b * S + row) * D + h * 64 + df * 16 + l15] = f2bf(vv);
        }
}

extern "C" void kernel_launch(void* const* d_in, const int* in_sizes, int n_in,
                              void* d_out, int out_size, void* d_ws, size_t ws_size,
                              hipStream_t stream)
{
    const float* q  = (const float*)d_in[0];
    const float* k  = (const float*)d_in[1];
    const float* v  = (const float*)d_in[2];
    const float* Wq = (const float*)d_in[3];
    const float* bq = (const float*)d_in[4];
    const float* Wk = (const float*)d_in[5];
    const float* bk = (const float*)d_in[6];
    const float* Wv = (const float*)d_in[7];
    const float* bv = (const float*)d_in[8];
    const float* Wo = (const float*)d_in[9];
    const float* bo = (const float*)d_in[10];

    const int M = 4096, N = 1024, K = 1024;
    const size_t nBS = (size_t)M * N;     // 4.19M elements
    const size_t nW  = (size_t)N * K;     // 1.05M elements

    unsigned short* qb  = (unsigned short*)d_ws;
    unsigned short* kb  = qb  + nBS;
    unsigned short* vb  = kb  + nBS;
    unsigned short* Wqb = vb  + nBS;
    unsigned short* Wkb = Wqb + nW;
    unsigned short* Wvb = Wkb + nW;
    unsigned short* Wob = Wvb + nW;
    unsigned short* Qp  = Wob + nW;
    unsigned short* Kp  = Qp  + nBS;
    unsigned short* Vp  = Kp  + nBS;
    unsigned short* Ct  = qb;             // alias: qb dead after QKV GEMM

    // 1) convert all fp32 operands to bf16
    dim3 gc(1024, 1, 7);
    conv_bf16<<<gc, 256, 0, stream>>>(q, k, v, Wq, Wk, Wv, Wo,
                                      qb, kb, vb, Wqb, Wkb, Wvb, Wob,
                                      (int)(nBS / 4), (int)(nW / 4));

    // 2) QKV projections (fused, z=3)
    dim3 g1(N / 128, M / 128, 3);
    gemm_bf16<true><<<g1, 256, 0, stream>>>(qb, kb, vb, Wqb, Wkb, Wvb,
                                            bq, bk, bv, Qp, Kp, Vp, M, N, K);

    // 3) attention (longest q-tiles first)
    dim3 g2(32, 32);
    attn_causal<<<g2, 256, 0, stream>>>(Qp, Kp, Vp, Ct);

    // 4) output projection (fp32 out)
    dim3 g3(N / 128, M / 128, 1);
    gemm_bf16<false><<<g3, 256, 0, stream>>>(Ct, Ct, Ct, Wob, Wob, Wob,
                                             bo, bo, bo, d_out, d_out, d_out, M, N, K);
}

// Round 4
// 263.775 us; speedup vs baseline: 1.3464x; 1.3091x over previous
//
#include <hip/hip_runtime.h>
#include <hip/hip_bf16.h>

using f32x4  = __attribute__((ext_vector_type(4))) float;
using short8 = __attribute__((ext_vector_type(8))) short;
using us8    = __attribute__((ext_vector_type(8))) unsigned short;
using us4    = __attribute__((ext_vector_type(4))) unsigned short;
using fl4    = __attribute__((ext_vector_type(4))) float;

__device__ __forceinline__ unsigned short f2bf(float f){
    unsigned u = __builtin_bit_cast(unsigned, f);
    u += 0x7FFF + ((u >> 16) & 1);
    return (unsigned short)(u >> 16);
}

__device__ __forceinline__ void gload16(const unsigned short* g, unsigned short* l) {
    __builtin_amdgcn_global_load_lds(
        (const __attribute__((address_space(1))) unsigned int*)g,
        (__attribute__((address_space(3))) unsigned int*)l, 16, 0, 0);
}

// ---------------- fp32 -> bf16 conversion (z picks array) ----------------
__global__ __launch_bounds__(256)
void conv_bf16(const float* __restrict__ s0, const float* __restrict__ s1, const float* __restrict__ s2,
               const float* __restrict__ s3, const float* __restrict__ s4, const float* __restrict__ s5,
               const float* __restrict__ s6,
               unsigned short* __restrict__ d0, unsigned short* __restrict__ d1, unsigned short* __restrict__ d2,
               unsigned short* __restrict__ d3, unsigned short* __restrict__ d4, unsigned short* __restrict__ d5,
               unsigned short* __restrict__ d6,
               int nbig4, int nsml4)
{
    const int z = blockIdx.z;
    const float* s = (z==0)?s0:(z==1)?s1:(z==2)?s2:(z==3)?s3:(z==4)?s4:(z==5)?s5:s6;
    unsigned short* d = (z==0)?d0:(z==1)?d1:(z==2)?d2:(z==3)?d3:(z==4)?d4:(z==5)?d5:d6;
    const int n4 = (z < 3) ? nbig4 : nsml4;
    const int stride = gridDim.x * blockDim.x;
    for (int i = blockIdx.x * blockDim.x + threadIdx.x; i < n4; i += stride) {
        fl4 v = ((const fl4*)s)[i];
        us4 o = { f2bf(v[0]), f2bf(v[1]), f2bf(v[2]), f2bf(v[3]) };
        ((us4*)d)[i] = o;
    }
}

// ---------------- bf16 GEMM, 2-phase counted-vmcnt prefetch ----------------
// C = A @ W^T + bias. 128x128 tile, BK=64, 4 waves (2x2), double LDS buffer,
// stage(kt+1) issued BEFORE compute(kt); s_waitcnt vmcnt(8) (own 8 loads/tile).
template<bool OBF16>
__global__ __launch_bounds__(256, 2)
void gemm_bf16(const unsigned short* __restrict__ A0, const unsigned short* __restrict__ A1,
               const unsigned short* __restrict__ A2,
               const unsigned short* __restrict__ W0, const unsigned short* __restrict__ W1,
               const unsigned short* __restrict__ W2,
               const float* __restrict__ B0, const float* __restrict__ B1, const float* __restrict__ B2,
               void* __restrict__ O0, void* __restrict__ O1, void* __restrict__ O2,
               int M, int N, int K)
{
    const int z = blockIdx.z;
    const unsigned short* Ap = (z==0)?A0:(z==1)?A1:A2;
    const unsigned short* Wp = (z==0)?W0:(z==1)?W1:W2;
    const float* bp = (z==0)?B0:(z==1)?B1:B2;
    void* Op = (z==0)?O0:(z==1)?O1:O2;

    const int tid = threadIdx.x, lane = tid & 63, w = tid >> 6;
    const int wr = w >> 1, wc = w & 1;
    const int l15 = lane & 15, l4 = lane >> 4;
    const int bm = blockIdx.y, bn = blockIdx.x;

    __shared__ unsigned short As[2][128 * 64];
    __shared__ unsigned short Bs[2][128 * 64];

    f32x4 acc[4][4];
    #pragma unroll
    for (int i = 0; i < 4; i++)
        #pragma unroll
        for (int j = 0; j < 4; j++) acc[i][j] = (f32x4){0.f, 0.f, 0.f, 0.f};

    const int KT = K >> 6;
    const int srow = lane >> 3;        // 0..7 within chunk
    const int scol = (lane & 7) * 8;   // bf16 col

    auto stage = [&](int buf, int kt) {
        #pragma unroll
        for (int i = 0; i < 4; i++) {
            const int chunk = w * 4 + i;               // wave-uniform
            const int row = chunk * 8 + srow;
            gload16(Ap + (size_t)(bm * 128 + row) * K + kt * 64 + scol, &As[buf][chunk * 512]);
            gload16(Wp + (size_t)(bn * 128 + row) * K + kt * 64 + scol, &Bs[buf][chunk * 512]);
        }
    };

    stage(0, 0);
    int cur = 0;
    for (int kt = 0; kt < KT; ++kt) {
        if (kt + 1 < KT) {
            stage(cur ^ 1, kt + 1);
            asm volatile("s_waitcnt vmcnt(8)" ::: "memory");   // my 8 loads of kt done
        } else {
            asm volatile("s_waitcnt vmcnt(0)" ::: "memory");
        }
        __builtin_amdgcn_s_barrier();   // all waves' kt loads landed

        short8 af[4][2], bfr[4][2];
        #pragma unroll
        for (int mf = 0; mf < 4; mf++)
            #pragma unroll
            for (int kf = 0; kf < 2; kf++)
                af[mf][kf] = *(const short8*)&As[cur][(wr * 64 + mf * 16 + l15) * 64 + kf * 32 + l4 * 8];
        #pragma unroll
        for (int nf = 0; nf < 4; nf++)
            #pragma unroll
            for (int kf = 0; kf < 2; kf++)
                bfr[nf][kf] = *(const short8*)&Bs[cur][(wc * 64 + nf * 16 + l15) * 64 + kf * 32 + l4 * 8];
        #pragma unroll
        for (int mf = 0; mf < 4; mf++)
            #pragma unroll
            for (int nf = 0; nf < 4; nf++)
                #pragma unroll
                for (int kf = 0; kf < 2; kf++)
                    acc[mf][nf] = __builtin_amdgcn_mfma_f32_16x16x32_bf16(af[mf][kf], bfr[nf][kf], acc[mf][nf], 0, 0, 0);

        __builtin_amdgcn_s_barrier();   // compute(kt) done before buf overwrite
        cur ^= 1;
    }

    #pragma unroll
    for (int mf = 0; mf < 4; mf++) {
        int row = bm * 128 + wr * 64 + mf * 16 + l4 * 4;
        #pragma unroll
        for (int nf = 0; nf < 4; nf++) {
            int col = bn * 128 + wc * 64 + nf * 16 + l15;
            float bv = bp[col];
            #pragma unroll
            for (int r = 0; r < 4; r++) {
                float vv = acc[mf][nf][r] + bv;
                if constexpr (OBF16)
                    ((unsigned short*)Op)[(size_t)(row + r) * N + col] = f2bf(vv);
                else
                    ((float*)Op)[(size_t)(row + r) * N + col] = vv;
            }
        }
    }
}

// ---------------- causal flash attention, swapped QK^T, paired q-tiles ------
// Block = (pair, bh). Two phases: qt = pair, then qt = 31-pair -> 33 KV tiles
// per block uniformly. 4 waves x 16 q-rows per phase. S^T = mfma(K, Q):
// lane's l15 = its q-row; 16 P values per lane in registers -> in-register
// softmax with 4 cross-lane shuffles.
__global__ __launch_bounds__(256, 2)
void attn_causal(const unsigned short* __restrict__ Qp,
                 const unsigned short* __restrict__ Kp,
                 const unsigned short* __restrict__ Vp,
                 unsigned short* __restrict__ Ctx)
{
    const int S = 2048, D = 1024;
    const int bh = blockIdx.y, b = bh >> 4, h = bh & 15;
    const int pairIdx = blockIdx.x;               // 0..15
    const int tid = threadIdx.x, w = tid >> 6, lane = tid & 63;
    const int l15 = lane & 15, l4 = lane >> 4;

    __shared__ unsigned short Ks[64 * 64];        // [kv][d], row-swizzled
    __shared__ unsigned short Vt[64 * 64];        // [d][kv], d-group swizzled
    __shared__ unsigned short Ps[4][16 * 64];     // per-wave P [q][kv], q-swizzled

    const float sc = 0.125f * 1.44269504088896f;  // 1/sqrt(64) * log2(e)

    for (int phase = 0; phase < 2; ++phase) {
        const int qt = (phase == 0) ? pairIdx : 31 - pairIdx;
        const int nt = qt + 1;
        const int qbase = qt * 64 + w * 16;       // wave's first q-row
        const int qrow = qbase + l15;             // this lane's q-row

        short8 qf[2];
        #pragma unroll
        for (int kf = 0; kf < 2; kf++)
            qf[kf] = *(const short8*)(Qp + (size_t)(b * S + qrow) * D + h * 64 + kf * 32 + l4 * 8);

        float mrow = -3.0e38f, lrow = 0.f;
        f32x4 oacc[4];
        #pragma unroll
        for (int df = 0; df < 4; df++) oacc[df] = (f32x4){0.f, 0.f, 0.f, 0.f};

        us8 krg[2], vrg[2];
        #pragma unroll
        for (int i = 0; i < 2; i++) {
            int cc = i * 256 + tid, r = cc >> 3, d0 = (cc & 7) * 8;
            krg[i] = *(const us8*)(Kp + (size_t)(b * S + r) * D + h * 64 + d0);
            vrg[i] = *(const us8*)(Vp + (size_t)(b * S + r) * D + h * 64 + d0);
        }

        for (int t = 0; t < nt; ++t) {
            __syncthreads();   // protect LDS from previous tile's readers
            #pragma unroll
            for (int i = 0; i < 2; i++) {
                int cc = i * 256 + tid, r = cc >> 3, e = cc & 7, d0 = e * 8;
                int koff = (r * 128 + d0 * 2) ^ ((r & 7) << 4);
                *(us8*)((char*)Ks + koff) = krg[i];
                #pragma unroll
                for (int j = 0; j < 8; j++) {
                    int voff = ((d0 + j) * 128 + r * 2) ^ (e << 4);
                    *(unsigned short*)((char*)Vt + voff) = vrg[i][j];
                }
            }
            __syncthreads();   // publish

            if (t + 1 < nt) {
                #pragma unroll
                for (int i = 0; i < 2; i++) {
                    int cc = i * 256 + tid, r = cc >> 3, d0 = (cc & 7) * 8;
                    krg[i] = *(const us8*)(Kp + (size_t)(b * S + (t + 1) * 64 + r) * D + h * 64 + d0);
                    vrg[i] = *(const us8*)(Vp + (size_t)(b * S + (t + 1) * 64 + r) * D + h * 64 + d0);
                }
            }

            // S^T = K Q^T : sf[nf] col=l15=q, row=l4*4+r -> kv = nf*16+l4*4+r
            f32x4 sf[4];
            #pragma unroll
            for (int nf = 0; nf < 4; nf++) sf[nf] = (f32x4){0.f, 0.f, 0.f, 0.f};
            #pragma unroll
            for (int nf = 0; nf < 4; nf++)
                #pragma unroll
                for (int kf = 0; kf < 2; kf++) {
                    int row = nf * 16 + l15;
                    int off = (row * 128 + kf * 64 + l4 * 16) ^ ((row & 7) << 4);
                    short8 kfrag = *(const short8*)((const char*)Ks + off);
                    sf[nf] = __builtin_amdgcn_mfma_f32_16x16x32_bf16(kfrag, qf[kf], sf[nf], 0, 0, 0);
                }

            // scale + causal mask (only diagonal tile needs it)
            float pf[16];
            const bool domask = (t == nt - 1);
            #pragma unroll
            for (int nf = 0; nf < 4; nf++)
                #pragma unroll
                for (int r = 0; r < 4; r++) {
                    float x = sf[nf][r] * sc;
                    if (domask) {
                        int kv = t * 64 + nf * 16 + l4 * 4 + r;
                        if (kv > qrow) x = -3.0e38f;
                    }
                    pf[nf * 4 + r] = x;
                }

            // in-register row softmax (row = this lane's q-row)
            float t8[8];
            #pragma unroll
            for (int i = 0; i < 8; i++) t8[i] = fmaxf(pf[i], pf[i + 8]);
            float t4a = fmaxf(t8[0], t8[4]), t4b = fmaxf(t8[1], t8[5]);
            float t4c = fmaxf(t8[2], t8[6]), t4d = fmaxf(t8[3], t8[7]);
            float pm = fmaxf(fmaxf(t4a, t4b), fmaxf(t4c, t4d));
            pm = fmaxf(pm, __shfl_xor(pm, 16));
            pm = fmaxf(pm, __shfl_xor(pm, 32));
            float mn = fmaxf(mrow, pm);
            float fs = exp2f(mrow - mn);
            float ps = 0.f;
            #pragma unroll
            for (int i = 0; i < 16; i++) { float e = exp2f(pf[i] - mn); pf[i] = e; ps += e; }
            ps += __shfl_xor(ps, 16);
            ps += __shfl_xor(ps, 32);
            lrow = lrow * fs + ps;
            mrow = mn;

            // rescale O: oacc rows are q' = l4*4+r -> fetch fs from lane q'
            float fsq[4];
            #pragma unroll
            for (int r = 0; r < 4; r++) fsq[r] = __shfl(fs, l4 * 4 + r);
            #pragma unroll
            for (int df = 0; df < 4; df++)
                #pragma unroll
                for (int r = 0; r < 4; r++) oacc[df][r] *= fsq[r];

            // P -> LDS (bf16, b64 writes), layout [q][kv] swizzled by q
            #pragma unroll
            for (int nf = 0; nf < 4; nf++) {
                us4 pk = { f2bf(pf[nf * 4 + 0]), f2bf(pf[nf * 4 + 1]),
                           f2bf(pf[nf * 4 + 2]), f2bf(pf[nf * 4 + 3]) };
                int off = (l15 * 128 + (nf * 16 + l4 * 4) * 2) ^ ((l15 & 7) << 4);
                *(us4*)((char*)Ps[w] + off) = pk;
            }

            // O += P V
            #pragma unroll
            for (int kf = 0; kf < 2; kf++) {
                int offp = (l15 * 128 + kf * 64 + l4 * 16) ^ ((l15 & 7) << 4);
                short8 pa = *(const short8*)((const char*)Ps[w] + offp);
                #pragma unroll
                for (int df = 0; df < 4; df++) {
                    int d = df * 16 + l15;
                    int offv = (d * 128 + kf * 64 + l4 * 16) ^ (((d >> 3) & 7) << 4);
                    short8 vb = *(const short8*)((const char*)Vt + offv);
                    oacc[df] = __builtin_amdgcn_mfma_f32_16x16x32_bf16(pa, vb, oacc[df], 0, 0, 0);
                }
            }
        }

        // epilogue: oacc row q' = l4*4+r, col d = df*16+l15
        float inv = 1.0f / lrow;
        float invq[4];
        #pragma unroll
        for (int r = 0; r < 4; r++) invq[r] = __shfl(inv, l4 * 4 + r);
        #pragma unroll
        for (int df = 0; df < 4; df++)
            #pragma unroll
            for (int r = 0; r < 4; r++) {
                int row = qt * 64 + w * 16 + l4 * 4 + r;
                Ctx[(size_t)(b * S + row) * D + h * 64 + df * 16 + l15] = f2bf(oacc[df][r] * invq[r]);
            }
    }
}

extern "C" void kernel_launch(void* const* d_in, const int* in_sizes, int n_in,
                              void* d_out, int out_size, void* d_ws, size_t ws_size,
                              hipStream_t stream)
{
    const float* q  = (const float*)d_in[0];
    const float* k  = (const float*)d_in[1];
    const float* v  = (const float*)d_in[2];
    const float* Wq = (const float*)d_in[3];
    const float* bq = (const float*)d_in[4];
    const float* Wk = (const float*)d_in[5];
    const float* bk = (const float*)d_in[6];
    const float* Wv = (const float*)d_in[7];
    const float* bv = (const float*)d_in[8];
    const float* Wo = (const float*)d_in[9];
    const float* bo = (const float*)d_in[10];

    const int M = 4096, N = 1024, K = 1024;
    const size_t nBS = (size_t)M * N;
    const size_t nW  = (size_t)N * K;

    unsigned short* qb  = (unsigned short*)d_ws;
    unsigned short* kb  = qb  + nBS;
    unsigned short* vb  = kb  + nBS;
    unsigned short* Wqb = vb  + nBS;
    unsigned short* Wkb = Wqb + nW;
    unsigned short* Wvb = Wkb + nW;
    unsigned short* Wob = Wvb + nW;
    unsigned short* Qp  = Wob + nW;
    unsigned short* Kp  = Qp  + nBS;
    unsigned short* Vp  = Kp  + nBS;
    unsigned short* Ct  = qb;             // alias: qb dead after QKV GEMM

    dim3 gc(1024, 1, 7);
    conv_bf16<<<gc, 256, 0, stream>>>(q, k, v, Wq, Wk, Wv, Wo,
                                      qb, kb, vb, Wqb, Wkb, Wvb, Wob,
                                      (int)(nBS / 4), (int)(nW / 4));

    dim3 g1(N / 128, M / 128, 3);
    gemm_bf16<true><<<g1, 256, 0, stream>>>(qb, kb, vb, Wqb, Wkb, Wvb,
                                            bq, bk, bv, Qp, Kp, Vp, M, N, K);

    dim3 g2(16, 32);
    attn_causal<<<g2, 256, 0, stream>>>(Qp, Kp, Vp, Ct);

    dim3 g3(N / 128, M / 128, 1);
    gemm_bf16<false><<<g3, 256, 0, stream>>>(Ct, Ct, Ct, Wob, Wob, Wob,
                                             bo, bo, bo, d_out, d_out, d_out, M, N, K);
}